// Round 9
// baseline (664.601 us; speedup 1.0000x reference)
//
#include <hip/hip_runtime.h>
#include <hip/hip_bf16.h>
#include <cfloat>

#define B_ 256
#define N_ 1024
#define D_ 1024
#define E_ 8
#define L_ 1000

typedef float f32x4 __attribute__((ext_vector_type(4)));
typedef short bf16x8 __attribute__((ext_vector_type(8)));

__device__ inline unsigned short f2bf(float f) {
  unsigned u = __builtin_bit_cast(unsigned, f);
  u += 0x7fffu + ((u >> 16) & 1u);  // round-to-nearest-even
  return (unsigned short)(u >> 16);
}

// ---------------- Kernel 1: gate scores (memory-bound, reads 1 GiB) -------
// grid 8192 x 256, output layout identical to R4 ([e][b*N+n], 32 rows/block).
// Each wave: 8 rows as 2 groups of 4 (acc[32] + f[2][4] ~ 85 VGPR -> 5-6
// waves/SIMD vs R4's ~4), with explicit double-buffered prefetch: chunk c+1's
// 4 float4 loads issue before chunk c's 128-FMA block, so global loads stay
// in flight continuously (incl. across the per-group butterfly).
__global__ __launch_bounds__(256) void k_gate(const float* __restrict__ feat,
                                              const float* __restrict__ gate_w,
                                              float* __restrict__ scores) {
  __shared__ float gwT[E_ * D_];  // gwT[e][d], 32 KB
  __shared__ float sm[8][132];    // [e][32 rows of this block], padded
  const int t = threadIdx.x;
  const float4* gw4 = (const float4*)gate_w;  // flat idx = d*8+e
#pragma unroll
  for (int j = 0; j < 8; ++j) {
    const int idx4 = j * 256 + t;
    const float4 v = gw4[idx4];
    const int d = idx4 >> 1, e0 = (idx4 & 1) * 4;
    gwT[(e0 + 0) * D_ + d] = v.x;
    gwT[(e0 + 1) * D_ + d] = v.y;
    gwT[(e0 + 2) * D_ + d] = v.z;
    gwT[(e0 + 3) * D_ + d] = v.w;
  }
  __syncthreads();

  const int wave = t >> 6, lane = t & 63;
  const long rowBase = ((long)blockIdx.x * 4 + wave) * 8;
  const float* fbase = feat + rowBase * D_ + lane * 4;

  // bitrev5: value index v = r*8+e held by lane (lane<32) after the 5-step
  // butterfly + cross-half add (R5-verified reduction).
  const int L5 = lane & 31;
  const int v = ((L5 & 1) << 4) | ((L5 & 2) << 2) | (L5 & 4) |
                ((L5 & 8) >> 2) | ((L5 & 16) >> 4);

  float4 f[2][4];
#pragma unroll
  for (int r = 0; r < 4; ++r) f[0][r] = *(const float4*)(fbase + r * D_);

  float acc[32];  // acc[r*8+e], r in 0..3 of current group
#pragma unroll
  for (int j = 0; j < 32; ++j) acc[j] = 0.f;

#pragma unroll
  for (int c = 0; c < 8; ++c) {      // chunk c: group g=c>>2 (rows g*4..+3),
    const int cur = c & 1;           //          d-range it=c&3 (it*256..+255)
    if (c < 7) {
      const int cn = c + 1, gn = cn >> 2, itn = cn & 3;
#pragma unroll
      for (int r = 0; r < 4; ++r)
        f[cur ^ 1][r] = *(const float4*)(fbase + (gn * 4 + r) * D_ + itn * 256);
    }
    const int g = c >> 2, it = c & 3;
#pragma unroll
    for (int e = 0; e < 8; ++e) {
      const float4 gv = *(const float4*)(&gwT[e * D_ + it * 256 + lane * 4]);
#pragma unroll
      for (int r = 0; r < 4; ++r) {
        acc[r * 8 + e] = fmaf(f[cur][r].x, gv.x,
                         fmaf(f[cur][r].y, gv.y,
                         fmaf(f[cur][r].z, gv.z,
                         fmaf(f[cur][r].w, gv.w, acc[r * 8 + e]))));
      }
    }
    if (it == 3) {
      // 5-step distributed butterfly over 32 values + cross-half add.
#pragma unroll
      for (int s = 0; s < 5; ++s) {
        const int m = 1 << s;
        const int half = 16 >> s;
        const bool up = (lane & m) != 0;
#pragma unroll
        for (int j = 0; j < half; ++j) {
          float keep = up ? acc[j + half] : acc[j];
          float send = up ? acc[j] : acc[j + half];
          acc[j] = keep + __shfl_xor(send, m, 64);
        }
      }
      acc[0] += __shfl_xor(acc[0], 32, 64);
      if (lane < 32) sm[v & 7][wave * 8 + g * 4 + (v >> 3)] = acc[0];
      if (c < 7) {
#pragma unroll
        for (int j = 0; j < 32; ++j) acc[j] = 0.f;
      }
    }
  }
  __syncthreads();
  const int te = t >> 5, tr = t & 31;
  scores[(size_t)te * (B_ * N_) + (long)blockIdx.x * 32 + tr] = sm[te][tr];
  // gate_b intentionally unused: softmax over N is invariant to a per-expert
  // additive constant, so it cancels from top_v and comb_w.
}

// ------- Kernel 2: fused per-(b,e) softmax-over-N top-3 + weighted gather --
// grid 2048 (one block per pair), 256 threads. Wave 0: coalesced read of the
// 1024-score column, top-3 + Z; then all 4 waves gather 3 feature rows.
__global__ __launch_bounds__(256) void k_topk_gather(
    const float* __restrict__ scores, const float* __restrict__ feat,
    unsigned short* __restrict__ wf) {
  __shared__ int sI[3];
  __shared__ float sC[3];
  const int t = threadIdx.x, w = t >> 6, lane = t & 63;
  const int pair = blockIdx.x;
  const int b = pair >> 3, e = pair & 7;

  if (w == 0) {
    const float* s = scores + (size_t)e * (B_ * N_) + (size_t)b * N_;
    float v[16];  // v[j*4+c] = score at n = j*256 + lane*4 + c
#pragma unroll
    for (int j = 0; j < 4; ++j) {
      const float4 x = *(const float4*)(s + j * 256 + lane * 4);
      v[j * 4 + 0] = x.x; v[j * 4 + 1] = x.y;
      v[j * 4 + 2] = x.z; v[j * 4 + 3] = x.w;
    }

    float M[3];
    int I[3];
    float Z = 0.f;
#pragma unroll
    for (int k = 0; k < 3; ++k) {
      float lm = -FLT_MAX;
      int ln = 0x7fffffff;
#pragma unroll
      for (int j = 0; j < 4; ++j)
#pragma unroll
        for (int c = 0; c < 4; ++c) {
          const float val = v[j * 4 + c];
          if (val > lm) { lm = val; ln = j * 256 + lane * 4 + c; }
        }
#pragma unroll
      for (int s2 = 1; s2 < 64; s2 <<= 1) {
        float om = __shfl_xor(lm, s2, 64);
        int on = __shfl_xor(ln, s2, 64);
        if (om > lm || (om == lm && on < ln)) { lm = om; ln = on; }
      }
      M[k] = lm;
      I[k] = ln;
      if (k == 0) {  // global max in lm; sum exp before masking
        float se = 0.f;
#pragma unroll
        for (int j = 0; j < 16; ++j) se += expf(v[j] - lm);
#pragma unroll
        for (int s2 = 1; s2 < 64; s2 <<= 1) se += __shfl_xor(se, s2, 64);
        Z = se;
      }
      const int slot = ln >> 8, owner = (ln >> 2) & 63, comp = ln & 3;
#pragma unroll
      for (int j = 0; j < 4; ++j)
#pragma unroll
        for (int c = 0; c < 4; ++c)
          if (j == slot && c == comp && owner == lane)
            v[j * 4 + c] = -FLT_MAX;
    }

    if (lane == 0) {
      const float p0 = 1.f / Z;                 // exp(M0-M0)/Z
      const float p1 = expf(M[1] - M[0]) / Z;
      const float p2 = expf(M[2] - M[0]) / Z;
      const float c1 = expf(p1 - p0);           // softmax over [p0,p1,p2]
      const float c2 = expf(p2 - p0);
      const float den = 1.f + c1 + c2;
      sI[0] = I[0]; sI[1] = I[1]; sI[2] = I[2];
      sC[0] = 1.f / den; sC[1] = c1 / den; sC[2] = c2 / den;
    }
  }
  __syncthreads();

  const int i0 = sI[0], i1 = sI[1], i2 = sI[2];
  const float c0 = sC[0], c1 = sC[1], c2 = sC[2];
  const float* f = feat + (size_t)b * N_ * D_;
  const int d = t * 4;
  const float4 x = *(const float4*)(f + (size_t)i0 * D_ + d);
  const float4 y = *(const float4*)(f + (size_t)i1 * D_ + d);
  const float4 z = *(const float4*)(f + (size_t)i2 * D_ + d);
  ushort4 o;
  o.x = f2bf(c0 * x.x + c1 * y.x + c2 * z.x);
  o.y = f2bf(c0 * x.y + c1 * y.y + c2 * z.y);
  o.z = f2bf(c0 * x.z + c1 * y.z + c2 * z.z);
  o.w = f2bf(c0 * x.w + c1 * y.w + c2 * z.w);
  *(ushort4*)(wf + (size_t)pair * D_ + d) = o;
}

// ---------------- Kernel 3: classifier GEMM via bf16 MFMA (R4-proven) -----
// part[e][b][l] = sum_d wf[b,e,d]*cls_w[e,l,d].
// BM=128 x BN=64 x BK=64, grid = 256 (8e x 2bt x 16lt), bt at stride 16 so
// the two blocks sharing a cls_w tile land on the SAME XCD (16 % 8 == 0).
// 512 threads = 8 waves (4x2), each wave a 32x32 sub-tile (2x2 frags of
// 16x16x32 bf16 MFMA) -> 2 waves/SIMD so ds_read and MFMA overlap.
// LDS as 16B granules, XOR-swizzled: granule g stored at (g ^ (row&7)).
__global__ __launch_bounds__(512) void k_cls(const unsigned short* __restrict__ wf,
                                             const float* __restrict__ cls_w,
                                             float* __restrict__ part) {
  __shared__ uint4 Ag[2][128 * 8];  // 2 x 16 KB: [row(b)][8 granules of 8 bf16]
  __shared__ uint4 Bg[2][64 * 8];   // 2 x  8 KB: [row(l)][8 granules]

  const int bx = blockIdx.x;
  const int e = bx >> 5, bt = (bx >> 4) & 1, lt = bx & 15;
  const int m0 = bt * 128, l0 = lt * 64;
  const int t = threadIdx.x;
  const int w = t >> 6, lane = t & 63;
  const int wm = w >> 1, wn = w & 1;  // wave tile: rows wm*32, cols wn*32

  // staging maps
  const int ar = t >> 2, ag2 = t & 3;  // A: 128 rows, 2 granules per thread
  const int br = t >> 3, bq = t & 7;   // B: 64 rows, 1 granule per thread
  const int lg = (l0 + br < L_) ? (l0 + br) : (L_ - 1);  // clamp OOB rows
  const unsigned short* agp = wf + ((size_t)(m0 + ar) * E_ + e) * D_ + ag2 * 16;
  const float* bgp = cls_w + ((size_t)e * L_ + lg) * D_ + bq * 8;

  uint4 areg[2];
  float4 breg[2];

  auto load_regs = [&](int step) {
    const int d0 = step * 64;
    areg[0] = *(const uint4*)(agp + d0);
    areg[1] = *(const uint4*)(agp + d0 + 8);
    breg[0] = *(const float4*)(bgp + d0);
    breg[1] = *(const float4*)(bgp + d0 + 4);
  };

  auto write_lds = [&](int c) {
#pragma unroll
    for (int j = 0; j < 2; ++j)
      Ag[c][ar * 8 + ((ag2 * 2 + j) ^ (ar & 7))] = areg[j];
    uint4 p;
    p.x = (unsigned)f2bf(breg[0].x) | ((unsigned)f2bf(breg[0].y) << 16);
    p.y = (unsigned)f2bf(breg[0].z) | ((unsigned)f2bf(breg[0].w) << 16);
    p.z = (unsigned)f2bf(breg[1].x) | ((unsigned)f2bf(breg[1].y) << 16);
    p.w = (unsigned)f2bf(breg[1].z) | ((unsigned)f2bf(breg[1].w) << 16);
    Bg[c][br * 8 + (bq ^ (br & 7))] = p;
  };

  f32x4 acc[2][2];
#pragma unroll
  for (int m = 0; m < 2; ++m)
#pragma unroll
    for (int n = 0; n < 2; ++n) acc[m][n] = (f32x4){0.f, 0.f, 0.f, 0.f};

  const int l15 = lane & 15, lhi = lane >> 4;

  load_regs(0);
  for (int step = 0; step < 16; ++step) {
    const int c = step & 1;
    write_lds(c);
    if (step < 15) load_regs(step + 1);
    __syncthreads();
#pragma unroll
    for (int ks = 0; ks < 2; ++ks) {
      bf16x8 a[2], b[2];
#pragma unroll
      for (int m = 0; m < 2; ++m) {
        const int row = wm * 32 + m * 16 + l15;
        a[m] = __builtin_bit_cast(bf16x8,
                 Ag[c][row * 8 + ((ks * 4 + lhi) ^ (row & 7))]);
      }
#pragma unroll
      for (int n = 0; n < 2; ++n) {
        const int row = wn * 32 + n * 16 + l15;
        b[n] = __builtin_bit_cast(bf16x8,
                 Bg[c][row * 8 + ((ks * 4 + lhi) ^ (row & 7))]);
      }
#pragma unroll
      for (int m = 0; m < 2; ++m)
#pragma unroll
        for (int n = 0; n < 2; ++n)
          acc[m][n] = __builtin_amdgcn_mfma_f32_16x16x32_bf16(
              a[m], b[n], acc[m][n], 0, 0, 0);
    }
    __syncthreads();
  }

  // C/D layout: col = lane&15, row = (lane>>4)*4 + j   [m89-verified]
#pragma unroll
  for (int m = 0; m < 2; ++m) {
#pragma unroll
    for (int n = 0; n < 2; ++n) {
      const int col = l0 + wn * 32 + n * 16 + l15;
      if (col < L_) {
#pragma unroll
        for (int j = 0; j < 4; ++j) {
          const int row = m0 + wm * 32 + m * 16 + lhi * 4 + j;
          part[((size_t)e * B_ + row) * L_ + col] = acc[m][n][j];
        }
      }
    }
  }
}

// ---------------- Kernel 4: reduce over experts + bias --------------------
__global__ __launch_bounds__(256) void k_reduce(const float* __restrict__ part,
                                                const float* __restrict__ cls_b,
                                                float* __restrict__ out) {
  const int idx = blockIdx.x * 256 + threadIdx.x;
  if (idx >= B_ * L_) return;
  const int l = idx % L_;
  float s = 0.f, bias = 0.f;
#pragma unroll
  for (int e = 0; e < 8; ++e) {
    s += part[(long)e * (B_ * L_) + idx];
    bias += cls_b[e * L_ + l];
  }
  out[idx] = (s + bias) * 0.125f;
}

extern "C" void kernel_launch(void* const* d_in, const int* in_sizes, int n_in,
                              void* d_out, int out_size, void* d_ws, size_t ws_size,
                              hipStream_t stream) {
  const float* feat   = (const float*)d_in[0];
  const float* gate_w = (const float*)d_in[1];
  // d_in[2] = gate_b: mathematically cancels (softmax over N), unused.
  const float* cls_w  = (const float*)d_in[3];
  const float* cls_b  = (const float*)d_in[4];
  float* out = (float*)d_out;

  char* ws = (char*)d_ws;
  // [0, 8.39MB): scores_e [e][b][n] (k1/k2), reused as part (k3/k4)
  // [8.39MB, +4.2MB): wf (bf16)
  float*          scores = (float*)ws;
  float*          part   = (float*)ws;  // scores dead after k_topk_gather
  unsigned short* wfb    = (unsigned short*)(ws + 8388608);

  k_gate<<<8192, 256, 0, stream>>>(feat, gate_w, scores);
  k_topk_gather<<<2048, 256, 0, stream>>>(scores, feat, wfb);
  k_cls<<<256, 512, 0, stream>>>(wfb, cls_w, part);
  k_reduce<<<1000, 256, 0, stream>>>(part, cls_b, out);
}

// Round 11
// 222.459 us; speedup vs baseline: 2.9875x; 2.9875x over previous
//
#include <hip/hip_runtime.h>
#include <hip/hip_bf16.h>
#include <cfloat>

#define B_ 256
#define N_ 1024
#define D_ 1024
#define E_ 8
#define L_ 1000

typedef float f32x4 __attribute__((ext_vector_type(4)));
typedef short bf16x8 __attribute__((ext_vector_type(8)));

__device__ inline unsigned short f2bf(float f) {
  unsigned u = __builtin_bit_cast(unsigned, f);
  u += 0x7fffu + ((u >> 16) & 1u);  // round-to-nearest-even
  return (unsigned short)(u >> 16);
}

__device__ inline float4 ntload4(const float* p) {
  f32x4 v = __builtin_nontemporal_load((const f32x4*)p);  // ext_vector is legal
  return __builtin_bit_cast(float4, v);
}

// ---------------- Kernel 1: gate scores (memory-bound, reads 1 GiB) -------
// R4 structure verbatim (proven 238.5us total); only change: feat loads are
// nontemporal so the 1 GB stream doesn't evict gate_w/scores from L2.
// grid 8192 x 256. Each wave: 8 rows x gate_w(D,8) -> 64 sums, butterfly
// reduce, then LDS reassembly so scores land in [e][b*N+n] layout.
__global__ __launch_bounds__(256) void k_gate(const float* __restrict__ feat,
                                              const float* __restrict__ gate_w,
                                              float* __restrict__ scores) {
  __shared__ float gwT[E_ * D_];  // gwT[e][d], 32 KB
  __shared__ float sm[8][132];    // [e][32 rows of this block], padded
  const int t = threadIdx.x;
#pragma unroll
  for (int j = 0; j < 32; ++j) {
    int idx = j * 256 + t;  // flat gate_w index = d*8 + e
    int e = idx & 7, d = idx >> 3;
    gwT[e * D_ + d] = gate_w[idx];
  }
  __syncthreads();

  const int wave = t >> 6, lane = t & 63;
  const long rowBase = ((long)blockIdx.x * 4 + wave) * 8;
  const float* fbase = feat + rowBase * D_;

  float acc[64];  // acc[r*8+e]
#pragma unroll
  for (int j = 0; j < 64; ++j) acc[j] = 0.f;

#pragma unroll
  for (int it = 0; it < 4; ++it) {
    const int d0 = it * 256 + lane * 4;
    float4 f[8];
#pragma unroll
    for (int r = 0; r < 8; ++r) f[r] = ntload4(fbase + r * D_ + d0);
#pragma unroll
    for (int e = 0; e < 8; ++e) {
      const float4 g = *(const float4*)(&gwT[e * D_ + d0]);
#pragma unroll
      for (int r = 0; r < 8; ++r) {
        acc[r * 8 + e] = fmaf(f[r].x, g.x,
                         fmaf(f[r].y, g.y,
                         fmaf(f[r].z, g.z,
                         fmaf(f[r].w, g.w, acc[r * 8 + e]))));
      }
    }
  }

  // Distributed butterfly: lane L ends holding full sum of value bitrev6(L).
#pragma unroll
  for (int s = 0; s < 6; ++s) {
    const int m = 1 << s;
    const int half = 32 >> s;
    const bool up = (lane & m) != 0;
#pragma unroll
    for (int j = 0; j < half; ++j) {
      float keep = up ? acc[j + half] : acc[j];
      float send = up ? acc[j] : acc[j + half];
      float recv = __shfl_xor(send, m, 64);
      acc[j] = keep + recv;
    }
  }
  const int idx = ((lane & 1) << 5) | ((lane & 2) << 3) | ((lane & 4) << 1) |
                  ((lane & 8) >> 1) | ((lane & 16) >> 3) | ((lane & 32) >> 5);
  // idx = r*8 + e for rows rowBase+r.  Reassemble to e-major via LDS.
  sm[idx & 7][wave * 8 + (idx >> 3)] = acc[0];
  __syncthreads();
  const int te = t >> 5, tr = t & 31;
  scores[(size_t)te * (B_ * N_) + (long)blockIdx.x * 32 + tr] = sm[te][tr];
  // gate_b intentionally unused: softmax over N is invariant to a per-expert
  // additive constant, so it cancels from top_v and comb_w.
}

// ------- Kernel 2: fused per-(b,e) softmax-over-N top-3 + weighted gather --
// grid 2048 (one block per pair), 256 threads. Wave 0: coalesced read of the
// 1024-score column, top-3 + Z; then all 4 waves gather 3 feature rows.
__global__ __launch_bounds__(256) void k_topk_gather(
    const float* __restrict__ scores, const float* __restrict__ feat,
    unsigned short* __restrict__ wf) {
  __shared__ int sI[3];
  __shared__ float sC[3];
  const int t = threadIdx.x, w = t >> 6, lane = t & 63;
  const int pair = blockIdx.x;
  const int b = pair >> 3, e = pair & 7;

  if (w == 0) {
    const float* s = scores + (size_t)e * (B_ * N_) + (size_t)b * N_;
    float v[16];  // v[j*4+c] = score at n = j*256 + lane*4 + c
#pragma unroll
    for (int j = 0; j < 4; ++j) {
      const float4 x = *(const float4*)(s + j * 256 + lane * 4);
      v[j * 4 + 0] = x.x; v[j * 4 + 1] = x.y;
      v[j * 4 + 2] = x.z; v[j * 4 + 3] = x.w;
    }

    float M[3];
    int I[3];
    float Z = 0.f;
#pragma unroll
    for (int k = 0; k < 3; ++k) {
      float lm = -FLT_MAX;
      int ln = 0x7fffffff;
#pragma unroll
      for (int j = 0; j < 4; ++j)
#pragma unroll
        for (int c = 0; c < 4; ++c) {
          const float val = v[j * 4 + c];
          if (val > lm) { lm = val; ln = j * 256 + lane * 4 + c; }
        }
#pragma unroll
      for (int s2 = 1; s2 < 64; s2 <<= 1) {
        float om = __shfl_xor(lm, s2, 64);
        int on = __shfl_xor(ln, s2, 64);
        if (om > lm || (om == lm && on < ln)) { lm = om; ln = on; }
      }
      M[k] = lm;
      I[k] = ln;
      if (k == 0) {  // global max in lm; sum exp before masking
        float se = 0.f;
#pragma unroll
        for (int j = 0; j < 16; ++j) se += expf(v[j] - lm);
#pragma unroll
        for (int s2 = 1; s2 < 64; s2 <<= 1) se += __shfl_xor(se, s2, 64);
        Z = se;
      }
      const int slot = ln >> 8, owner = (ln >> 2) & 63, comp = ln & 3;
#pragma unroll
      for (int j = 0; j < 4; ++j)
#pragma unroll
        for (int c = 0; c < 4; ++c)
          if (j == slot && c == comp && owner == lane)
            v[j * 4 + c] = -FLT_MAX;
    }

    if (lane == 0) {
      const float p0 = 1.f / Z;                 // exp(M0-M0)/Z
      const float p1 = expf(M[1] - M[0]) / Z;
      const float p2 = expf(M[2] - M[0]) / Z;
      const float c1 = expf(p1 - p0);           // softmax over [p0,p1,p2]
      const float c2 = expf(p2 - p0);
      const float den = 1.f + c1 + c2;
      sI[0] = I[0]; sI[1] = I[1]; sI[2] = I[2];
      sC[0] = 1.f / den; sC[1] = c1 / den; sC[2] = c2 / den;
    }
  }
  __syncthreads();

  const int i0 = sI[0], i1 = sI[1], i2 = sI[2];
  const float c0 = sC[0], c1 = sC[1], c2 = sC[2];
  const float* f = feat + (size_t)b * N_ * D_;
  const int d = t * 4;
  const float4 x = *(const float4*)(f + (size_t)i0 * D_ + d);
  const float4 y = *(const float4*)(f + (size_t)i1 * D_ + d);
  const float4 z = *(const float4*)(f + (size_t)i2 * D_ + d);
  ushort4 o;
  o.x = f2bf(c0 * x.x + c1 * y.x + c2 * z.x);
  o.y = f2bf(c0 * x.y + c1 * y.y + c2 * z.y);
  o.z = f2bf(c0 * x.z + c1 * y.z + c2 * z.z);
  o.w = f2bf(c0 * x.w + c1 * y.w + c2 * z.w);
  *(ushort4*)(wf + (size_t)pair * D_ + d) = o;
}

// ---------------- Kernel 3: classifier GEMM via bf16 MFMA (R4-proven) -----
// part[e][b][l] = sum_d wf[b,e,d]*cls_w[e,l,d].
// BM=128 x BN=64 x BK=64, grid = 256 (8e x 2bt x 16lt), bt at stride 16 so
// the two blocks sharing a cls_w tile land on the SAME XCD (16 % 8 == 0).
// 512 threads = 8 waves (4x2), each wave a 32x32 sub-tile (2x2 frags of
// 16x16x32 bf16 MFMA) -> 2 waves/SIMD so ds_read and MFMA overlap.
// LDS as 16B granules, XOR-swizzled: granule g stored at (g ^ (row&7)).
__global__ __launch_bounds__(512) void k_cls(const unsigned short* __restrict__ wf,
                                             const float* __restrict__ cls_w,
                                             float* __restrict__ part) {
  __shared__ uint4 Ag[2][128 * 8];  // 2 x 16 KB: [row(b)][8 granules of 8 bf16]
  __shared__ uint4 Bg[2][64 * 8];   // 2 x  8 KB: [row(l)][8 granules]

  const int bx = blockIdx.x;
  const int e = bx >> 5, bt = (bx >> 4) & 1, lt = bx & 15;
  const int m0 = bt * 128, l0 = lt * 64;
  const int t = threadIdx.x;
  const int w = t >> 6, lane = t & 63;
  const int wm = w >> 1, wn = w & 1;  // wave tile: rows wm*32, cols wn*32

  // staging maps
  const int ar = t >> 2, ag2 = t & 3;  // A: 128 rows, 2 granules per thread
  const int br = t >> 3, bq = t & 7;   // B: 64 rows, 1 granule per thread
  const int lg = (l0 + br < L_) ? (l0 + br) : (L_ - 1);  // clamp OOB rows
  const unsigned short* agp = wf + ((size_t)(m0 + ar) * E_ + e) * D_ + ag2 * 16;
  const float* bgp = cls_w + ((size_t)e * L_ + lg) * D_ + bq * 8;

  uint4 areg[2];
  float4 breg[2];

  auto load_regs = [&](int step) {
    const int d0 = step * 64;
    areg[0] = *(const uint4*)(agp + d0);
    areg[1] = *(const uint4*)(agp + d0 + 8);
    breg[0] = *(const float4*)(bgp + d0);
    breg[1] = *(const float4*)(bgp + d0 + 4);
  };

  auto write_lds = [&](int c) {
#pragma unroll
    for (int j = 0; j < 2; ++j)
      Ag[c][ar * 8 + ((ag2 * 2 + j) ^ (ar & 7))] = areg[j];
    uint4 p;
    p.x = (unsigned)f2bf(breg[0].x) | ((unsigned)f2bf(breg[0].y) << 16);
    p.y = (unsigned)f2bf(breg[0].z) | ((unsigned)f2bf(breg[0].w) << 16);
    p.z = (unsigned)f2bf(breg[1].x) | ((unsigned)f2bf(breg[1].y) << 16);
    p.w = (unsigned)f2bf(breg[1].z) | ((unsigned)f2bf(breg[1].w) << 16);
    Bg[c][br * 8 + (bq ^ (br & 7))] = p;
  };

  f32x4 acc[2][2];
#pragma unroll
  for (int m = 0; m < 2; ++m)
#pragma unroll
    for (int n = 0; n < 2; ++n) acc[m][n] = (f32x4){0.f, 0.f, 0.f, 0.f};

  const int l15 = lane & 15, lhi = lane >> 4;

  load_regs(0);
  for (int step = 0; step < 16; ++step) {
    const int c = step & 1;
    write_lds(c);
    if (step < 15) load_regs(step + 1);
    __syncthreads();
#pragma unroll
    for (int ks = 0; ks < 2; ++ks) {
      bf16x8 a[2], b[2];
#pragma unroll
      for (int m = 0; m < 2; ++m) {
        const int row = wm * 32 + m * 16 + l15;
        a[m] = __builtin_bit_cast(bf16x8,
                 Ag[c][row * 8 + ((ks * 4 + lhi) ^ (row & 7))]);
      }
#pragma unroll
      for (int n = 0; n < 2; ++n) {
        const int row = wn * 32 + n * 16 + l15;
        b[n] = __builtin_bit_cast(bf16x8,
                 Bg[c][row * 8 + ((ks * 4 + lhi) ^ (row & 7))]);
      }
#pragma unroll
      for (int m = 0; m < 2; ++m)
#pragma unroll
        for (int n = 0; n < 2; ++n)
          acc[m][n] = __builtin_amdgcn_mfma_f32_16x16x32_bf16(
              a[m], b[n], acc[m][n], 0, 0, 0);
    }
    __syncthreads();
  }

  // C/D layout: col = lane&15, row = (lane>>4)*4 + j   [m89-verified]
#pragma unroll
  for (int m = 0; m < 2; ++m) {
#pragma unroll
    for (int n = 0; n < 2; ++n) {
      const int col = l0 + wn * 32 + n * 16 + l15;
      if (col < L_) {
#pragma unroll
        for (int j = 0; j < 4; ++j) {
          const int row = m0 + wm * 32 + m * 16 + lhi * 4 + j;
          part[((size_t)e * B_ + row) * L_ + col] = acc[m][n][j];
        }
      }
    }
  }
}

// ---------------- Kernel 4: reduce over experts + bias --------------------
__global__ __launch_bounds__(256) void k_reduce(const float* __restrict__ part,
                                                const float* __restrict__ cls_b,
                                                float* __restrict__ out) {
  const int idx = blockIdx.x * 256 + threadIdx.x;
  if (idx >= B_ * L_) return;
  const int l = idx % L_;
  float s = 0.f, bias = 0.f;
#pragma unroll
  for (int e = 0; e < 8; ++e) {
    s += part[(long)e * (B_ * L_) + idx];
    bias += cls_b[e * L_ + l];
  }
  out[idx] = (s + bias) * 0.125f;
}

extern "C" void kernel_launch(void* const* d_in, const int* in_sizes, int n_in,
                              void* d_out, int out_size, void* d_ws, size_t ws_size,
                              hipStream_t stream) {
  const float* feat   = (const float*)d_in[0];
  const float* gate_w = (const float*)d_in[1];
  // d_in[2] = gate_b: mathematically cancels (softmax over N), unused.
  const float* cls_w  = (const float*)d_in[3];
  const float* cls_b  = (const float*)d_in[4];
  float* out = (float*)d_out;

  char* ws = (char*)d_ws;
  // [0, 8.39MB): scores_e [e][b][n] (k1/k2), reused as part (k3/k4)
  // [8.39MB, +4.2MB): wf (bf16)
  float*          scores = (float*)ws;
  float*          part   = (float*)ws;  // scores dead after k_topk_gather
  unsigned short* wfb    = (unsigned short*)(ws + 8388608);

  k_gate<<<8192, 256, 0, stream>>>(feat, gate_w, scores);
  k_topk_gather<<<2048, 256, 0, stream>>>(scores, feat, wfb);
  k_cls<<<256, 512, 0, stream>>>(wfb, cls_w, part);
  k_reduce<<<1000, 256, 0, stream>>>(part, cls_b, out);
}

// Round 12
// 216.543 us; speedup vs baseline: 3.0691x; 1.0273x over previous
//
#include <hip/hip_runtime.h>
#include <hip/hip_bf16.h>
#include <cfloat>

#define B_ 256
#define N_ 1024
#define D_ 1024
#define E_ 8
#define L_ 1000

typedef float f32x4 __attribute__((ext_vector_type(4)));
typedef short bf16x8 __attribute__((ext_vector_type(8)));

__device__ inline unsigned short f2bf(float f) {
  unsigned u = __builtin_bit_cast(unsigned, f);
  u += 0x7fffu + ((u >> 16) & 1u);  // round-to-nearest-even
  return (unsigned short)(u >> 16);
}

__device__ inline float4 ntload4(const float* p) {
  f32x4 v = __builtin_nontemporal_load((const f32x4*)p);
  return __builtin_bit_cast(float4, v);
}
__device__ inline float ntload1(const float* p) {
  return __builtin_nontemporal_load(p);
}

// ---------------- Kernel 1: gate scores (memory-bound, reads 1 GiB) -------
// R11 structure (proven 222.5us total): NT feat loads keep the 1 GB stream
// out of L2 so gate_w staging + score writes stay cache-resident.
// Only change vs R11: gwT staged with float4 loads (8 vec loads/thread vs
// 32 scalars); LDS writes 2-way aliased (free, m136).
// grid 8192 x 256. Each wave: 8 rows x gate_w(D,8) -> 64 sums, butterfly
// reduce, then LDS reassembly so scores land in [e][b*N+n] layout.
__global__ __launch_bounds__(256) void k_gate(const float* __restrict__ feat,
                                              const float* __restrict__ gate_w,
                                              float* __restrict__ scores) {
  __shared__ float gwT[E_ * D_];  // gwT[e][d], 32 KB
  __shared__ float sm[8][132];    // [e][32 rows of this block], padded
  const int t = threadIdx.x;
  const float4* gw4 = (const float4*)gate_w;  // flat idx = d*8+e
#pragma unroll
  for (int j = 0; j < 8; ++j) {
    const int idx4 = j * 256 + t;
    const float4 v = gw4[idx4];
    const int d = idx4 >> 1, e0 = (idx4 & 1) * 4;
    gwT[(e0 + 0) * D_ + d] = v.x;
    gwT[(e0 + 1) * D_ + d] = v.y;
    gwT[(e0 + 2) * D_ + d] = v.z;
    gwT[(e0 + 3) * D_ + d] = v.w;
  }
  __syncthreads();

  const int wave = t >> 6, lane = t & 63;
  const long rowBase = ((long)blockIdx.x * 4 + wave) * 8;
  const float* fbase = feat + rowBase * D_;

  float acc[64];  // acc[r*8+e]
#pragma unroll
  for (int j = 0; j < 64; ++j) acc[j] = 0.f;

#pragma unroll
  for (int it = 0; it < 4; ++it) {
    const int d0 = it * 256 + lane * 4;
    float4 f[8];
#pragma unroll
    for (int r = 0; r < 8; ++r) f[r] = ntload4(fbase + r * D_ + d0);
#pragma unroll
    for (int e = 0; e < 8; ++e) {
      const float4 g = *(const float4*)(&gwT[e * D_ + d0]);
#pragma unroll
      for (int r = 0; r < 8; ++r) {
        acc[r * 8 + e] = fmaf(f[r].x, g.x,
                         fmaf(f[r].y, g.y,
                         fmaf(f[r].z, g.z,
                         fmaf(f[r].w, g.w, acc[r * 8 + e]))));
      }
    }
  }

  // Distributed butterfly: lane L ends holding full sum of value bitrev6(L).
#pragma unroll
  for (int s = 0; s < 6; ++s) {
    const int m = 1 << s;
    const int half = 32 >> s;
    const bool up = (lane & m) != 0;
#pragma unroll
    for (int j = 0; j < half; ++j) {
      float keep = up ? acc[j + half] : acc[j];
      float send = up ? acc[j] : acc[j + half];
      float recv = __shfl_xor(send, m, 64);
      acc[j] = keep + recv;
    }
  }
  const int idx = ((lane & 1) << 5) | ((lane & 2) << 3) | ((lane & 4) << 1) |
                  ((lane & 8) >> 1) | ((lane & 16) >> 3) | ((lane & 32) >> 5);
  // idx = r*8 + e for rows rowBase+r.  Reassemble to e-major via LDS.
  sm[idx & 7][wave * 8 + (idx >> 3)] = acc[0];
  __syncthreads();
  const int te = t >> 5, tr = t & 31;
  scores[(size_t)te * (B_ * N_) + (long)blockIdx.x * 32 + tr] = sm[te][tr];
  // gate_b intentionally unused: softmax over N is invariant to a per-expert
  // additive constant, so it cancels from top_v and comb_w.
}

// ------- Kernel 2: fused per-(b,e) softmax-over-N top-3 + weighted gather --
// grid 2048 (one block per pair), 256 threads. Wave 0: coalesced read of the
// 1024-score column, top-3 + Z; then all 4 waves gather 3 feature rows.
// NT loads: scores column is read once; gathered feat rows have no reuse
// (and feat is not L2-resident after k_gate's NT stream).
__global__ __launch_bounds__(256) void k_topk_gather(
    const float* __restrict__ scores, const float* __restrict__ feat,
    unsigned short* __restrict__ wf) {
  __shared__ int sI[3];
  __shared__ float sC[3];
  const int t = threadIdx.x, w = t >> 6, lane = t & 63;
  const int pair = blockIdx.x;
  const int b = pair >> 3, e = pair & 7;

  if (w == 0) {
    const float* s = scores + (size_t)e * (B_ * N_) + (size_t)b * N_;
    float v[16];  // v[j*4+c] = score at n = j*256 + lane*4 + c
#pragma unroll
    for (int j = 0; j < 4; ++j) {
      const float4 x = ntload4(s + j * 256 + lane * 4);
      v[j * 4 + 0] = x.x; v[j * 4 + 1] = x.y;
      v[j * 4 + 2] = x.z; v[j * 4 + 3] = x.w;
    }

    float M[3];
    int I[3];
    float Z = 0.f;
#pragma unroll
    for (int k = 0; k < 3; ++k) {
      float lm = -FLT_MAX;
      int ln = 0x7fffffff;
#pragma unroll
      for (int j = 0; j < 4; ++j)
#pragma unroll
        for (int c = 0; c < 4; ++c) {
          const float val = v[j * 4 + c];
          if (val > lm) { lm = val; ln = j * 256 + lane * 4 + c; }
        }
#pragma unroll
      for (int s2 = 1; s2 < 64; s2 <<= 1) {
        float om = __shfl_xor(lm, s2, 64);
        int on = __shfl_xor(ln, s2, 64);
        if (om > lm || (om == lm && on < ln)) { lm = om; ln = on; }
      }
      M[k] = lm;
      I[k] = ln;
      if (k == 0) {  // global max in lm; sum exp before masking
        float se = 0.f;
#pragma unroll
        for (int j = 0; j < 16; ++j) se += expf(v[j] - lm);
#pragma unroll
        for (int s2 = 1; s2 < 64; s2 <<= 1) se += __shfl_xor(se, s2, 64);
        Z = se;
      }
      const int slot = ln >> 8, owner = (ln >> 2) & 63, comp = ln & 3;
#pragma unroll
      for (int j = 0; j < 4; ++j)
#pragma unroll
        for (int c = 0; c < 4; ++c)
          if (j == slot && c == comp && owner == lane)
            v[j * 4 + c] = -FLT_MAX;
    }

    if (lane == 0) {
      const float p0 = 1.f / Z;                 // exp(M0-M0)/Z
      const float p1 = expf(M[1] - M[0]) / Z;
      const float p2 = expf(M[2] - M[0]) / Z;
      const float c1 = expf(p1 - p0);           // softmax over [p0,p1,p2]
      const float c2 = expf(p2 - p0);
      const float den = 1.f + c1 + c2;
      sI[0] = I[0]; sI[1] = I[1]; sI[2] = I[2];
      sC[0] = 1.f / den; sC[1] = c1 / den; sC[2] = c2 / den;
    }
  }
  __syncthreads();

  const int i0 = sI[0], i1 = sI[1], i2 = sI[2];
  const float c0 = sC[0], c1 = sC[1], c2 = sC[2];
  const float* f = feat + (size_t)b * N_ * D_;
  const int d = t * 4;
  const float4 x = ntload4(f + (size_t)i0 * D_ + d);
  const float4 y = ntload4(f + (size_t)i1 * D_ + d);
  const float4 z = ntload4(f + (size_t)i2 * D_ + d);
  ushort4 o;
  o.x = f2bf(c0 * x.x + c1 * y.x + c2 * z.x);
  o.y = f2bf(c0 * x.y + c1 * y.y + c2 * z.y);
  o.z = f2bf(c0 * x.z + c1 * y.z + c2 * z.z);
  o.w = f2bf(c0 * x.w + c1 * y.w + c2 * z.w);
  *(ushort4*)(wf + (size_t)pair * D_ + d) = o;
}

// ---------------- Kernel 3: classifier GEMM via bf16 MFMA (R4-proven) -----
// part[e][b][l] = sum_d wf[b,e,d]*cls_w[e,l,d].
// BM=128 x BN=64 x BK=64, grid = 256 (8e x 2bt x 16lt), bt at stride 16 so
// the two blocks sharing a cls_w tile land on the SAME XCD (16 % 8 == 0).
// 512 threads = 8 waves (4x2), each wave a 32x32 sub-tile (2x2 frags of
// 16x16x32 bf16 MFMA) -> 2 waves/SIMD so ds_read and MFMA overlap.
// LDS as 16B granules, XOR-swizzled: granule g stored at (g ^ (row&7)).
// No NT here: wf and cls_w tiles are reused across blocks via L2.
__global__ __launch_bounds__(512) void k_cls(const unsigned short* __restrict__ wf,
                                             const float* __restrict__ cls_w,
                                             float* __restrict__ part) {
  __shared__ uint4 Ag[2][128 * 8];  // 2 x 16 KB: [row(b)][8 granules of 8 bf16]
  __shared__ uint4 Bg[2][64 * 8];   // 2 x  8 KB: [row(l)][8 granules]

  const int bx = blockIdx.x;
  const int e = bx >> 5, bt = (bx >> 4) & 1, lt = bx & 15;
  const int m0 = bt * 128, l0 = lt * 64;
  const int t = threadIdx.x;
  const int w = t >> 6, lane = t & 63;
  const int wm = w >> 1, wn = w & 1;  // wave tile: rows wm*32, cols wn*32

  // staging maps
  const int ar = t >> 2, ag2 = t & 3;  // A: 128 rows, 2 granules per thread
  const int br = t >> 3, bq = t & 7;   // B: 64 rows, 1 granule per thread
  const int lg = (l0 + br < L_) ? (l0 + br) : (L_ - 1);  // clamp OOB rows
  const unsigned short* agp = wf + ((size_t)(m0 + ar) * E_ + e) * D_ + ag2 * 16;
  const float* bgp = cls_w + ((size_t)e * L_ + lg) * D_ + bq * 8;

  uint4 areg[2];
  float4 breg[2];

  auto load_regs = [&](int step) {
    const int d0 = step * 64;
    areg[0] = *(const uint4*)(agp + d0);
    areg[1] = *(const uint4*)(agp + d0 + 8);
    breg[0] = *(const float4*)(bgp + d0);
    breg[1] = *(const float4*)(bgp + d0 + 4);
  };

  auto write_lds = [&](int c) {
#pragma unroll
    for (int j = 0; j < 2; ++j)
      Ag[c][ar * 8 + ((ag2 * 2 + j) ^ (ar & 7))] = areg[j];
    uint4 p;
    p.x = (unsigned)f2bf(breg[0].x) | ((unsigned)f2bf(breg[0].y) << 16);
    p.y = (unsigned)f2bf(breg[0].z) | ((unsigned)f2bf(breg[0].w) << 16);
    p.z = (unsigned)f2bf(breg[1].x) | ((unsigned)f2bf(breg[1].y) << 16);
    p.w = (unsigned)f2bf(breg[1].z) | ((unsigned)f2bf(breg[1].w) << 16);
    Bg[c][br * 8 + (bq ^ (br & 7))] = p;
  };

  f32x4 acc[2][2];
#pragma unroll
  for (int m = 0; m < 2; ++m)
#pragma unroll
    for (int n = 0; n < 2; ++n) acc[m][n] = (f32x4){0.f, 0.f, 0.f, 0.f};

  const int l15 = lane & 15, lhi = lane >> 4;

  load_regs(0);
  for (int step = 0; step < 16; ++step) {
    const int c = step & 1;
    write_lds(c);
    if (step < 15) load_regs(step + 1);
    __syncthreads();
#pragma unroll
    for (int ks = 0; ks < 2; ++ks) {
      bf16x8 a[2], b[2];
#pragma unroll
      for (int m = 0; m < 2; ++m) {
        const int row = wm * 32 + m * 16 + l15;
        a[m] = __builtin_bit_cast(bf16x8,
                 Ag[c][row * 8 + ((ks * 4 + lhi) ^ (row & 7))]);
      }
#pragma unroll
      for (int n = 0; n < 2; ++n) {
        const int row = wn * 32 + n * 16 + l15;
        b[n] = __builtin_bit_cast(bf16x8,
                 Bg[c][row * 8 + ((ks * 4 + lhi) ^ (row & 7))]);
      }
#pragma unroll
      for (int m = 0; m < 2; ++m)
#pragma unroll
        for (int n = 0; n < 2; ++n)
          acc[m][n] = __builtin_amdgcn_mfma_f32_16x16x32_bf16(
              a[m], b[n], acc[m][n], 0, 0, 0);
    }
    __syncthreads();
  }

  // C/D layout: col = lane&15, row = (lane>>4)*4 + j   [m89-verified]
#pragma unroll
  for (int m = 0; m < 2; ++m) {
#pragma unroll
    for (int n = 0; n < 2; ++n) {
      const int col = l0 + wn * 32 + n * 16 + l15;
      if (col < L_) {
#pragma unroll
        for (int j = 0; j < 4; ++j) {
          const int row = m0 + wm * 32 + m * 16 + lhi * 4 + j;
          part[((size_t)e * B_ + row) * L_ + col] = acc[m][n][j];
        }
      }
    }
  }
}

// ---------------- Kernel 4: reduce over experts + bias --------------------
__global__ __launch_bounds__(256) void k_reduce(const float* __restrict__ part,
                                                const float* __restrict__ cls_b,
                                                float* __restrict__ out) {
  const int idx = blockIdx.x * 256 + threadIdx.x;
  if (idx >= B_ * L_) return;
  const int l = idx % L_;
  float s = 0.f, bias = 0.f;
#pragma unroll
  for (int e = 0; e < 8; ++e) {
    s += ntload1(part + (size_t)e * (B_ * L_) + idx);  // streamed once
    bias += cls_b[e * L_ + l];
  }
  out[idx] = (s + bias) * 0.125f;
}

extern "C" void kernel_launch(void* const* d_in, const int* in_sizes, int n_in,
                              void* d_out, int out_size, void* d_ws, size_t ws_size,
                              hipStream_t stream) {
  const float* feat   = (const float*)d_in[0];
  const float* gate_w = (const float*)d_in[1];
  // d_in[2] = gate_b: mathematically cancels (softmax over N), unused.
  const float* cls_w  = (const float*)d_in[3];
  const float* cls_b  = (const float*)d_in[4];
  float* out = (float*)d_out;

  char* ws = (char*)d_ws;
  // [0, 8.39MB): scores_e [e][b][n] (k1/k2), reused as part (k3/k4)
  // [8.39MB, +4.2MB): wf (bf16)
  float*          scores = (float*)ws;
  float*          part   = (float*)ws;  // scores dead after k_topk_gather
  unsigned short* wfb    = (unsigned short*)(ws + 8388608);

  k_gate<<<8192, 256, 0, stream>>>(feat, gate_w, scores);
  k_topk_gather<<<2048, 256, 0, stream>>>(scores, feat, wfb);
  k_cls<<<256, 512, 0, stream>>>(wfb, cls_w, part);
  k_reduce<<<1000, 256, 0, stream>>>(part, cls_b, out);
}